// Round 1
// baseline (206.172 us; speedup 1.0000x reference)
//
#include <hip/hip_runtime.h>
#include <float.h>
#include <math.h>

#define B_NUM 64
#define P_NUM 8732
#define T_NUM 16
#define C_NUM 81
#define RPB   64                       // rows per block in CE kernel
#define NBLK2 ((B_NUM * P_NUM) / RPB)  // 8732

__device__ __forceinline__ float smooth_l1(float d) {
    float ad = fabsf(d);
    return (ad < 1.0f) ? 0.5f * d * d : ad - 0.5f;
}

// ---------------------------------------------------------------------------
// K1: per-batch matching, conf_t, loc loss over positives
// ---------------------------------------------------------------------------
__global__ __launch_bounds__(256) void k_match(
    const float* __restrict__ loc, const float* __restrict__ priors,
    const float* __restrict__ truths, const int* __restrict__ labels,
    int* __restrict__ conf_t, int* __restrict__ num_pos,
    float* __restrict__ loss_l_b)
{
    __shared__ float s_t[T_NUM][4];
    __shared__ int   s_lab[T_NUM];
    __shared__ float s_bto[P_NUM];
    __shared__ short s_bti[P_NUM];
    __shared__ float s_rv[4 * T_NUM];
    __shared__ int   s_ri[4 * T_NUM];
    __shared__ int   s_bp[T_NUM];
    __shared__ float s_red[4];
    __shared__ int   s_redi[4];

    const int b = blockIdx.x;
    const int tid = threadIdx.x;
    const int lane = tid & 63, wv = tid >> 6;

    if (tid < T_NUM * 4) ((float*)s_t)[tid] = truths[b * T_NUM * 4 + tid];
    if (tid < T_NUM)     s_lab[tid] = labels[b * T_NUM + tid];
    __syncthreads();

    // per-thread best prior per truth (first-occurrence: ascending p, strict >)
    float bpv[T_NUM]; int bpi[T_NUM];
#pragma unroll
    for (int t = 0; t < T_NUM; ++t) { bpv[t] = -1.0f; bpi[t] = 0; }

    const float4* pr4 = (const float4*)priors;
    for (int p = tid; p < P_NUM; p += 256) {
        float4 pr = pr4[p];
        float px0 = pr.x - 0.5f * pr.z, py0 = pr.y - 0.5f * pr.w;
        float px1 = pr.x + 0.5f * pr.z, py1 = pr.y + 0.5f * pr.w;
        float btv = -1.0f; int bti = 0;
#pragma unroll
        for (int t = 0; t < T_NUM; ++t) {
            float ix = fminf(s_t[t][2], px1) - fmaxf(s_t[t][0], px0);
            float iy = fminf(s_t[t][3], py1) - fmaxf(s_t[t][1], py0);
            ix = fmaxf(ix, 0.0f); iy = fmaxf(iy, 0.0f);
            float ov = ix * iy;
            if (ov > btv) { btv = ov; bti = t; }          // first max over t
            if (ov > bpv[t]) { bpv[t] = ov; bpi[t] = p; } // first max over p (local)
        }
        s_bto[p] = btv;
        s_bti[p] = (short)bti;
    }
    __syncthreads();

    // block-reduce best prior per truth: (max val, min idx on tie)
#pragma unroll
    for (int t = 0; t < T_NUM; ++t) {
        float v = bpv[t]; int i = bpi[t];
#pragma unroll
        for (int off = 32; off > 0; off >>= 1) {
            float ov = __shfl_down(v, off);
            int   oi = __shfl_down(i, off);
            if (ov > v || (ov == v && oi < i)) { v = ov; i = oi; }
        }
        if (lane == 0) { s_rv[wv * T_NUM + t] = v; s_ri[wv * T_NUM + t] = i; }
    }
    __syncthreads();
    if (tid < T_NUM) {
        float v = s_rv[tid]; int i = s_ri[tid];
        for (int w = 1; w < 4; ++w) {
            float ov = s_rv[w * T_NUM + tid]; int oi = s_ri[w * T_NUM + tid];
            if (ov > v || (ov == v && oi < i)) { v = ov; i = oi; }
        }
        s_bp[tid] = i;
    }
    __syncthreads();
    // forced assignment: serial over t, last t wins (matches last_j semantics)
    if (tid == 0) {
        for (int t = 0; t < T_NUM; ++t) {
            int pb = s_bp[t];
            s_bto[pb] = 2.0f;
            s_bti[pb] = (short)t;
        }
    }
    __syncthreads();

    // conf_t + loc loss over positives
    int cnt = 0; float lsum = 0.0f;
    const float4* loc4 = (const float4*)loc;
    for (int p = tid; p < P_NUM; p += 256) {
        float ovl = s_bto[p];
        int ti = (int)s_bti[p];
        int c = (ovl < 0.5f) ? 0 : (s_lab[ti] + 1);
        conf_t[b * P_NUM + p] = c;
        if (c > 0) {
            cnt++;
            float4 pr = pr4[p];
            float mx0 = s_t[ti][0], my0 = s_t[ti][1];
            float mx1 = s_t[ti][2], my1 = s_t[ti][3];
            float gx = ((mx0 + mx1) * 0.5f - pr.x) / (0.1f * pr.z);
            float gy = ((my0 + my1) * 0.5f - pr.y) / (0.1f * pr.w);
            float gw = logf((mx1 - mx0) / pr.z + 1e-10f) / 0.2f;
            float gh = logf((my1 - my0) / pr.w + 1e-10f) / 0.2f;
            float4 l = loc4[b * P_NUM + p];
            lsum += smooth_l1(l.x - gx) + smooth_l1(l.y - gy)
                  + smooth_l1(l.z - gw) + smooth_l1(l.w - gh);
        }
    }
#pragma unroll
    for (int off = 32; off > 0; off >>= 1) {
        lsum += __shfl_down(lsum, off);
        cnt  += __shfl_down(cnt, off);
    }
    if (lane == 0) { s_red[wv] = lsum; s_redi[wv] = cnt; }
    __syncthreads();
    if (tid == 0) {
        float L = 0.0f; int C2 = 0;
        for (int w = 0; w < 4; ++w) { L += s_red[w]; C2 += s_redi[w]; }
        num_pos[b] = C2;
        loss_l_b[b] = L;
    }
}

// ---------------------------------------------------------------------------
// K2: cross-entropy per prior (LDS-staged, coalesced)
// ---------------------------------------------------------------------------
__global__ __launch_bounds__(256) void k_ce(
    const float* __restrict__ conf, const int* __restrict__ conf_t,
    float* __restrict__ mined, float* __restrict__ posce_blk)
{
    __shared__ float s_c[RPB * C_NUM];   // 64*81 = 5184 floats = 20.7 KB
    __shared__ float s_red[4];
    const int blk = blockIdx.x, tid = threadIdx.x;
    const int r0 = blk * RPB;

    // coalesced float4 copy: base offset r0*81*4 bytes = 20736*blk -> 16B aligned
    const float4* src = (const float4*)(conf + (size_t)r0 * C_NUM);
    float4* dst = (float4*)s_c;
#pragma unroll 2
    for (int i = tid; i < (RPB * C_NUM) / 4; i += 256) dst[i] = src[i];
    __syncthreads();

    const int row = tid >> 2, sub = tid & 3;
    const int st = sub * 21, en = (sub == 3) ? C_NUM : (st + 21);
    const float* rp = s_c + row * C_NUM;

    float m = -FLT_MAX;
    for (int j = st; j < en; ++j) m = fmaxf(m, rp[j]);
    m = fmaxf(m, __shfl_xor(m, 1));
    m = fmaxf(m, __shfl_xor(m, 2));

    float s = 0.0f;
    for (int j = st; j < en; ++j) s += expf(rp[j] - m);
    s += __shfl_xor(s, 1);
    s += __shfl_xor(s, 2);

    float pce = 0.0f;
    if (sub == 0) {
        int r = r0 + row;
        int c = conf_t[r];
        float ce = m + logf(s) - rp[c];
        bool pos = c > 0;
        mined[r] = pos ? 0.0f : ce;
        if (pos) pce = ce;
    }
    const int lane = tid & 63, wv = tid >> 6;
#pragma unroll
    for (int off = 32; off > 0; off >>= 1) pce += __shfl_down(pce, off);
    if (lane == 0) s_red[wv] = pce;
    __syncthreads();
    if (tid == 0) posce_blk[blk] = s_red[0] + s_red[1] + s_red[2] + s_red[3];
}

// ---------------------------------------------------------------------------
// K3: stable top-num_neg extraction per batch (value desc, index asc)
// ---------------------------------------------------------------------------
__global__ __launch_bounds__(1024) void k_select(
    const float* __restrict__ mined, const int* __restrict__ num_pos,
    float* __restrict__ negsum_b)
{
    __shared__ float s_m[P_NUM];
    __shared__ float s_pv[16];
    __shared__ int   s_pi[16];
    __shared__ float s_wv;
    __shared__ int   s_wi;

    const int b = blockIdx.x, tid = threadIdx.x;
    const int lane = tid & 63, wv = tid >> 6;

    for (int p = tid; p < P_NUM; p += 1024) s_m[p] = mined[(size_t)b * P_NUM + p];
    __syncthreads();

    // per-thread local max (ascending p, strict > -> smallest idx on tie)
    float lv = -FLT_MAX; int li = 0;
    for (int p = tid; p < P_NUM; p += 1024) {
        float x = s_m[p];
        if (x > lv) { lv = x; li = p; }
    }

    int np = num_pos[b];
    int nn = 3 * np; if (nn > P_NUM - 1) nn = P_NUM - 1;

    float sum = 0.0f;
    for (int k = 0; k < nn; ++k) {
        float v = lv; int i = li;
#pragma unroll
        for (int off = 32; off > 0; off >>= 1) {
            float ov = __shfl_down(v, off);
            int   oi = __shfl_down(i, off);
            if (ov > v || (ov == v && oi < i)) { v = ov; i = oi; }
        }
        if (lane == 0) { s_pv[wv] = v; s_pi[wv] = i; }
        __syncthreads();
        if (tid == 0) {
            float bv = s_pv[0]; int bi = s_pi[0];
            for (int w = 1; w < 16; ++w) {
                float ov = s_pv[w]; int oi = s_pi[w];
                if (ov > bv || (ov == bv && oi < bi)) { bv = ov; bi = oi; }
            }
            s_wv = bv; s_wi = bi;
        }
        __syncthreads();
        int wi = s_wi;
        if (tid == 0) sum += s_wv;
        if ((wi & 1023) == tid) {
            s_m[wi] = -FLT_MAX;
            lv = -FLT_MAX; li = 0;
            for (int p = tid; p < P_NUM; p += 1024) {
                float x = s_m[p];
                if (x > lv) { lv = x; li = p; }
            }
        }
        __syncthreads();
    }
    if (tid == 0) negsum_b[b] = sum;
}

// ---------------------------------------------------------------------------
// K4: deterministic final reduction -> out[0]=loss_l/N, out[1]=loss_c/N
// ---------------------------------------------------------------------------
__global__ __launch_bounds__(256) void k_final(
    const float* __restrict__ posce_blk, int nblk,
    const float* __restrict__ loss_l_b, const float* __restrict__ negsum_b,
    const int* __restrict__ num_pos, float* __restrict__ out)
{
    __shared__ float s_a[4], s_b[4], s_c[4];
    __shared__ int   s_i[4];
    const int tid = threadIdx.x, lane = tid & 63, wv = tid >> 6;

    float pc = 0.0f;
    for (int i = tid; i < nblk; i += 256) pc += posce_blk[i];
    float ll = 0.0f, ns = 0.0f; int np = 0;
    if (tid < B_NUM) { ll = loss_l_b[tid]; ns = negsum_b[tid]; np = num_pos[tid]; }
#pragma unroll
    for (int off = 32; off > 0; off >>= 1) {
        pc += __shfl_down(pc, off);
        ll += __shfl_down(ll, off);
        ns += __shfl_down(ns, off);
        np += __shfl_down(np, off);
    }
    if (lane == 0) { s_a[wv] = pc; s_b[wv] = ll; s_c[wv] = ns; s_i[wv] = np; }
    __syncthreads();
    if (tid == 0) {
        float PC = 0.0f, LL = 0.0f, NS = 0.0f; int NP = 0;
        for (int w = 0; w < 4; ++w) { PC += s_a[w]; LL += s_b[w]; NS += s_c[w]; NP += s_i[w]; }
        float N = (float)(NP > 1 ? NP : 1);
        out[0] = LL / N;
        out[1] = (PC + NS) / N;
    }
}

// ---------------------------------------------------------------------------
extern "C" void kernel_launch(void* const* d_in, const int* in_sizes, int n_in,
                              void* d_out, int out_size, void* d_ws, size_t ws_size,
                              hipStream_t stream) {
    const float* loc    = (const float*)d_in[0];
    const float* conf   = (const float*)d_in[1];
    const float* priors = (const float*)d_in[2];
    const float* truths = (const float*)d_in[3];
    const int*   labels = (const int*)d_in[4];
    float* out = (float*)d_out;

    // workspace layout (4-byte words):
    // [0,64)            int   num_pos[B]
    // [64,128)          float loss_l_b[B]
    // [128,192)         float negsum_b[B]
    // [192,192+8732)    float posce_blk[NBLK2]
    // [8960, 8960+B*P)  int   conf_t
    // [8960+B*P, +B*P)  float mined
    int*   ws_i = (int*)d_ws;
    float* ws_f = (float*)d_ws;
    int*   num_pos   = ws_i;
    float* loss_l_b  = ws_f + 64;
    float* negsum_b  = ws_f + 128;
    float* posce_blk = ws_f + 192;
    int*   conf_t    = ws_i + 8960;
    float* mined     = ws_f + 8960 + B_NUM * P_NUM;

    k_match<<<B_NUM, 256, 0, stream>>>(loc, priors, truths, labels,
                                       conf_t, num_pos, loss_l_b);
    k_ce<<<NBLK2, 256, 0, stream>>>(conf, conf_t, mined, posce_blk);
    k_select<<<B_NUM, 1024, 0, stream>>>(mined, num_pos, negsum_b);
    k_final<<<1, 256, 0, stream>>>(posce_blk, NBLK2, loss_l_b, negsum_b, num_pos, out);
}

// Round 2
// 109.488 us; speedup vs baseline: 1.8831x; 1.8831x over previous
//
#include <hip/hip_runtime.h>
#include <float.h>
#include <math.h>

#define B_NUM 64
#define P_NUM 8732
#define T_NUM 16
#define C_NUM 81
#define RPB   64                       // rows per block in CE kernel
#define NBLK2 ((B_NUM * P_NUM) / RPB)  // 8732

__device__ __forceinline__ float smooth_l1(float d) {
    float ad = fabsf(d);
    return (ad < 1.0f) ? 0.5f * d * d : ad - 0.5f;
}

// ---------------------------------------------------------------------------
// K1: per-batch matching, conf_t, loc loss over positives
// ---------------------------------------------------------------------------
__global__ __launch_bounds__(256) void k_match(
    const float* __restrict__ loc, const float* __restrict__ priors,
    const float* __restrict__ truths, const int* __restrict__ labels,
    int* __restrict__ conf_t, int* __restrict__ num_pos,
    float* __restrict__ loss_l_b)
{
    __shared__ float s_t[T_NUM][4];
    __shared__ int   s_lab[T_NUM];
    __shared__ float s_bto[P_NUM];
    __shared__ short s_bti[P_NUM];
    __shared__ float s_rv[4 * T_NUM];
    __shared__ int   s_ri[4 * T_NUM];
    __shared__ int   s_bp[T_NUM];
    __shared__ float s_red[4];
    __shared__ int   s_redi[4];

    const int b = blockIdx.x;
    const int tid = threadIdx.x;
    const int lane = tid & 63, wv = tid >> 6;

    if (tid < T_NUM * 4) ((float*)s_t)[tid] = truths[b * T_NUM * 4 + tid];
    if (tid < T_NUM)     s_lab[tid] = labels[b * T_NUM + tid];
    __syncthreads();

    // per-thread best prior per truth (first-occurrence: ascending p, strict >)
    float bpv[T_NUM]; int bpi[T_NUM];
#pragma unroll
    for (int t = 0; t < T_NUM; ++t) { bpv[t] = -1.0f; bpi[t] = 0; }

    const float4* pr4 = (const float4*)priors;
    for (int p = tid; p < P_NUM; p += 256) {
        float4 pr = pr4[p];
        float px0 = pr.x - 0.5f * pr.z, py0 = pr.y - 0.5f * pr.w;
        float px1 = pr.x + 0.5f * pr.z, py1 = pr.y + 0.5f * pr.w;
        float btv = -1.0f; int bti = 0;
#pragma unroll
        for (int t = 0; t < T_NUM; ++t) {
            float ix = fminf(s_t[t][2], px1) - fmaxf(s_t[t][0], px0);
            float iy = fminf(s_t[t][3], py1) - fmaxf(s_t[t][1], py0);
            ix = fmaxf(ix, 0.0f); iy = fmaxf(iy, 0.0f);
            float ov = ix * iy;
            if (ov > btv) { btv = ov; bti = t; }          // first max over t
            if (ov > bpv[t]) { bpv[t] = ov; bpi[t] = p; } // first max over p (local)
        }
        s_bto[p] = btv;
        s_bti[p] = (short)bti;
    }
    __syncthreads();

    // block-reduce best prior per truth: (max val, min idx on tie)
#pragma unroll
    for (int t = 0; t < T_NUM; ++t) {
        float v = bpv[t]; int i = bpi[t];
#pragma unroll
        for (int off = 32; off > 0; off >>= 1) {
            float ov = __shfl_down(v, off);
            int   oi = __shfl_down(i, off);
            if (ov > v || (ov == v && oi < i)) { v = ov; i = oi; }
        }
        if (lane == 0) { s_rv[wv * T_NUM + t] = v; s_ri[wv * T_NUM + t] = i; }
    }
    __syncthreads();
    if (tid < T_NUM) {
        float v = s_rv[tid]; int i = s_ri[tid];
        for (int w = 1; w < 4; ++w) {
            float ov = s_rv[w * T_NUM + tid]; int oi = s_ri[w * T_NUM + tid];
            if (ov > v || (ov == v && oi < i)) { v = ov; i = oi; }
        }
        s_bp[tid] = i;
    }
    __syncthreads();
    // forced assignment: serial over t, last t wins (matches last_j semantics)
    if (tid == 0) {
        for (int t = 0; t < T_NUM; ++t) {
            int pb = s_bp[t];
            s_bto[pb] = 2.0f;
            s_bti[pb] = (short)t;
        }
    }
    __syncthreads();

    // conf_t + loc loss over positives
    int cnt = 0; float lsum = 0.0f;
    const float4* loc4 = (const float4*)loc;
    for (int p = tid; p < P_NUM; p += 256) {
        float ovl = s_bto[p];
        int ti = (int)s_bti[p];
        int c = (ovl < 0.5f) ? 0 : (s_lab[ti] + 1);
        conf_t[b * P_NUM + p] = c;
        if (c > 0) {
            cnt++;
            float4 pr = pr4[p];
            float mx0 = s_t[ti][0], my0 = s_t[ti][1];
            float mx1 = s_t[ti][2], my1 = s_t[ti][3];
            float gx = ((mx0 + mx1) * 0.5f - pr.x) / (0.1f * pr.z);
            float gy = ((my0 + my1) * 0.5f - pr.y) / (0.1f * pr.w);
            float gw = logf((mx1 - mx0) / pr.z + 1e-10f) / 0.2f;
            float gh = logf((my1 - my0) / pr.w + 1e-10f) / 0.2f;
            float4 l = loc4[b * P_NUM + p];
            lsum += smooth_l1(l.x - gx) + smooth_l1(l.y - gy)
                  + smooth_l1(l.z - gw) + smooth_l1(l.w - gh);
        }
    }
#pragma unroll
    for (int off = 32; off > 0; off >>= 1) {
        lsum += __shfl_down(lsum, off);
        cnt  += __shfl_down(cnt, off);
    }
    if (lane == 0) { s_red[wv] = lsum; s_redi[wv] = cnt; }
    __syncthreads();
    if (tid == 0) {
        float L = 0.0f; int C2 = 0;
        for (int w = 0; w < 4; ++w) { L += s_red[w]; C2 += s_redi[w]; }
        num_pos[b] = C2;
        loss_l_b[b] = L;
    }
}

// ---------------------------------------------------------------------------
// K2: cross-entropy per prior (LDS-staged, coalesced)
// ---------------------------------------------------------------------------
__global__ __launch_bounds__(256) void k_ce(
    const float* __restrict__ conf, const int* __restrict__ conf_t,
    float* __restrict__ mined, float* __restrict__ posce_blk)
{
    __shared__ float s_c[RPB * C_NUM];   // 64*81 = 5184 floats = 20.7 KB
    __shared__ float s_red[4];
    const int blk = blockIdx.x, tid = threadIdx.x;
    const int r0 = blk * RPB;

    // coalesced float4 copy: base offset r0*81*4 bytes = 20736*blk -> 16B aligned
    const float4* src = (const float4*)(conf + (size_t)r0 * C_NUM);
    float4* dst = (float4*)s_c;
#pragma unroll 2
    for (int i = tid; i < (RPB * C_NUM) / 4; i += 256) dst[i] = src[i];
    __syncthreads();

    const int row = tid >> 2, sub = tid & 3;
    const int st = sub * 21, en = (sub == 3) ? C_NUM : (st + 21);
    const float* rp = s_c + row * C_NUM;

    float m = -FLT_MAX;
    for (int j = st; j < en; ++j) m = fmaxf(m, rp[j]);
    m = fmaxf(m, __shfl_xor(m, 1));
    m = fmaxf(m, __shfl_xor(m, 2));

    float s = 0.0f;
    for (int j = st; j < en; ++j) s += expf(rp[j] - m);
    s += __shfl_xor(s, 1);
    s += __shfl_xor(s, 2);

    float pce = 0.0f;
    if (sub == 0) {
        int r = r0 + row;
        int c = conf_t[r];
        float ce = m + logf(s) - rp[c];
        bool pos = c > 0;
        mined[r] = pos ? 0.0f : ce;
        if (pos) pce = ce;
    }
    const int lane = tid & 63, wv = tid >> 6;
#pragma unroll
    for (int off = 32; off > 0; off >>= 1) pce += __shfl_down(pce, off);
    if (lane == 0) s_red[wv] = pce;
    __syncthreads();
    if (tid == 0) posce_blk[blk] = s_red[0] + s_red[1] + s_red[2] + s_red[3];
}

// ---------------------------------------------------------------------------
// K3: radix-select top-nn sum per batch.
// All mined values >= 0 so IEEE bits are order-preserving (as uint).
// Find v* = nn-th largest via 4x 8-bit radix passes (wave-private histograms),
// then sum = sum(x > v*) + (nn - cnt_gt) * v*  -- tie-exact for the SUM.
// ---------------------------------------------------------------------------
#define ELEMS 9  // ceil(8732/1024)

__global__ __launch_bounds__(1024) void k_select(
    const float* __restrict__ mined, const int* __restrict__ num_pos,
    float* __restrict__ negsum_b)
{
    __shared__ int   s_wh[16][256];   // wave-private histograms (16 KB)
    __shared__ int   s_hist[256];
    __shared__ int   s_sel, s_rem;
    __shared__ float s_sv[16];
    __shared__ int   s_sc[16];

    const int b = blockIdx.x, tid = threadIdx.x;
    const int lane = tid & 63, wv = tid >> 6;

    // values in registers, static indexing; pad with 0u (harmless: a 0-valued
    // boundary contributes 0 to the sum, and pads never outrank positives)
    unsigned int val[ELEMS];
#pragma unroll
    for (int i = 0; i < ELEMS; ++i) {
        int p = tid + i * 1024;
        val[i] = (p < P_NUM) ? __float_as_uint(mined[(size_t)b * P_NUM + p]) : 0u;
    }

    int np = num_pos[b];
    int nn = 3 * np; if (nn > P_NUM - 1) nn = P_NUM - 1;
    if (nn <= 0) { if (tid == 0) negsum_b[b] = 0.0f; return; }

    unsigned int prefix = 0;
    int k = nn;
#pragma unroll
    for (int shift = 24; shift >= 0; shift -= 8) {
        // clear wave-private histograms
        for (int i = tid; i < 16 * 256; i += 1024) ((int*)s_wh)[i] = 0;
        __syncthreads();
        const unsigned int pmask = (shift == 24) ? 0u : (0xFFFFFFFFu << (shift + 8));
#pragma unroll
        for (int i = 0; i < ELEMS; ++i) {
            unsigned int v = val[i];
            if ((v & pmask) == prefix)
                atomicAdd(&s_wh[wv][(v >> shift) & 0xFF], 1);
        }
        __syncthreads();
        // combine 16 wave histograms
        if (tid < 256) {
            int s = 0;
#pragma unroll
            for (int w = 0; w < 16; ++w) s += s_wh[w][tid];
            s_hist[tid] = s;
        }
        __syncthreads();
        // wave 0: suffix-scan over 256 bins, pick digit
        if (wv == 0) {
            int c0 = s_hist[4 * lane + 0], c1 = s_hist[4 * lane + 1];
            int c2 = s_hist[4 * lane + 2], c3 = s_hist[4 * lane + 3];
            int t3 = c3, t2 = c2 + t3, t1 = c1 + t2, t0 = c0 + t1;
            int g = t0, G = g;
#pragma unroll
            for (int off = 1; off < 64; off <<= 1) {
                int o = __shfl_down(G, off);
                if (lane + off < 64) G += o;
            }
            int above = G - g;
            int suf0 = t0 + above, suf1 = t1 + above;
            int suf2 = t2 + above, suf3 = t3 + above, suf4 = above;
            if (suf0 >= k && suf1 < k) { s_sel = 4 * lane + 0; s_rem = k - suf1; }
            if (suf1 >= k && suf2 < k) { s_sel = 4 * lane + 1; s_rem = k - suf2; }
            if (suf2 >= k && suf3 < k) { s_sel = 4 * lane + 2; s_rem = k - suf3; }
            if (suf3 >= k && suf4 < k) { s_sel = 4 * lane + 3; s_rem = k - suf4; }
        }
        __syncthreads();
        prefix |= ((unsigned int)s_sel) << shift;
        k = s_rem;
    }

    // sum of values strictly greater than v*, plus ties at v*
    float sgt = 0.0f; int cgt = 0;
#pragma unroll
    for (int i = 0; i < ELEMS; ++i) {
        unsigned int v = val[i];
        if (v > prefix) { sgt += __uint_as_float(v); cgt++; }
    }
#pragma unroll
    for (int off = 32; off > 0; off >>= 1) {
        sgt += __shfl_down(sgt, off);
        cgt += __shfl_down(cgt, off);
    }
    if (lane == 0) { s_sv[wv] = sgt; s_sc[wv] = cgt; }
    __syncthreads();
    if (tid == 0) {
        float S = 0.0f; int Ct = 0;
#pragma unroll
        for (int w = 0; w < 16; ++w) { S += s_sv[w]; Ct += s_sc[w]; }
        negsum_b[b] = S + (float)(nn - Ct) * __uint_as_float(prefix);
    }
}

// ---------------------------------------------------------------------------
// K4: deterministic final reduction -> out[0]=loss_l/N, out[1]=loss_c/N
// ---------------------------------------------------------------------------
__global__ __launch_bounds__(256) void k_final(
    const float* __restrict__ posce_blk, int nblk,
    const float* __restrict__ loss_l_b, const float* __restrict__ negsum_b,
    const int* __restrict__ num_pos, float* __restrict__ out)
{
    __shared__ float s_a[4], s_b[4], s_c[4];
    __shared__ int   s_i[4];
    const int tid = threadIdx.x, lane = tid & 63, wv = tid >> 6;

    float pc = 0.0f;
    for (int i = tid; i < nblk; i += 256) pc += posce_blk[i];
    float ll = 0.0f, ns = 0.0f; int np = 0;
    if (tid < B_NUM) { ll = loss_l_b[tid]; ns = negsum_b[tid]; np = num_pos[tid]; }
#pragma unroll
    for (int off = 32; off > 0; off >>= 1) {
        pc += __shfl_down(pc, off);
        ll += __shfl_down(ll, off);
        ns += __shfl_down(ns, off);
        np += __shfl_down(np, off);
    }
    if (lane == 0) { s_a[wv] = pc; s_b[wv] = ll; s_c[wv] = ns; s_i[wv] = np; }
    __syncthreads();
    if (tid == 0) {
        float PC = 0.0f, LL = 0.0f, NS = 0.0f; int NP = 0;
        for (int w = 0; w < 4; ++w) { PC += s_a[w]; LL += s_b[w]; NS += s_c[w]; NP += s_i[w]; }
        float N = (float)(NP > 1 ? NP : 1);
        out[0] = LL / N;
        out[1] = (PC + NS) / N;
    }
}

// ---------------------------------------------------------------------------
extern "C" void kernel_launch(void* const* d_in, const int* in_sizes, int n_in,
                              void* d_out, int out_size, void* d_ws, size_t ws_size,
                              hipStream_t stream) {
    const float* loc    = (const float*)d_in[0];
    const float* conf   = (const float*)d_in[1];
    const float* priors = (const float*)d_in[2];
    const float* truths = (const float*)d_in[3];
    const int*   labels = (const int*)d_in[4];
    float* out = (float*)d_out;

    int*   ws_i = (int*)d_ws;
    float* ws_f = (float*)d_ws;
    int*   num_pos   = ws_i;
    float* loss_l_b  = ws_f + 64;
    float* negsum_b  = ws_f + 128;
    float* posce_blk = ws_f + 192;
    int*   conf_t    = ws_i + 8960;
    float* mined     = ws_f + 8960 + B_NUM * P_NUM;

    k_match<<<B_NUM, 256, 0, stream>>>(loc, priors, truths, labels,
                                       conf_t, num_pos, loss_l_b);
    k_ce<<<NBLK2, 256, 0, stream>>>(conf, conf_t, mined, posce_blk);
    k_select<<<B_NUM, 1024, 0, stream>>>(mined, num_pos, negsum_b);
    k_final<<<1, 256, 0, stream>>>(posce_blk, NBLK2, loss_l_b, negsum_b, num_pos, out);
}

// Round 5
// 103.009 us; speedup vs baseline: 2.0015x; 1.0629x over previous
//
#include <hip/hip_runtime.h>
#include <float.h>
#include <math.h>

#define B_NUM 64
#define P_NUM 8732
#define T_NUM 16
#define C_NUM 81
#define RPB   64                       // rows per block in CE kernel
#define NBLK2 ((B_NUM * P_NUM) / RPB)  // 8732

__device__ __forceinline__ float smooth_l1(float d) {
    float ad = fabsf(d);
    return (ad < 1.0f) ? 0.5f * d * d : ad - 0.5f;
}

// ---------------------------------------------------------------------------
// K1: per-batch matching, conf_t, loc loss over positives
// ---------------------------------------------------------------------------
__global__ __launch_bounds__(256) void k_match(
    const float* __restrict__ loc, const float* __restrict__ priors,
    const float* __restrict__ truths, const int* __restrict__ labels,
    int* __restrict__ conf_t, int* __restrict__ num_pos,
    float* __restrict__ loss_l_b)
{
    __shared__ float s_t[T_NUM][4];
    __shared__ int   s_lab[T_NUM];
    __shared__ float s_bto[P_NUM];
    __shared__ short s_bti[P_NUM];
    __shared__ float s_rv[4 * T_NUM];
    __shared__ int   s_ri[4 * T_NUM];
    __shared__ int   s_bp[T_NUM];
    __shared__ float s_red[4];
    __shared__ int   s_redi[4];

    const int b = blockIdx.x;
    const int tid = threadIdx.x;
    const int lane = tid & 63, wv = tid >> 6;

    if (tid < T_NUM * 4) ((float*)s_t)[tid] = truths[b * T_NUM * 4 + tid];
    if (tid < T_NUM)     s_lab[tid] = labels[b * T_NUM + tid];
    __syncthreads();

    // per-thread best prior per truth (first-occurrence: ascending p, strict >)
    float bpv[T_NUM]; int bpi[T_NUM];
#pragma unroll
    for (int t = 0; t < T_NUM; ++t) { bpv[t] = -1.0f; bpi[t] = 0; }

    const float4* pr4 = (const float4*)priors;
    for (int p = tid; p < P_NUM; p += 256) {
        float4 pr = pr4[p];
        float px0 = pr.x - 0.5f * pr.z, py0 = pr.y - 0.5f * pr.w;
        float px1 = pr.x + 0.5f * pr.z, py1 = pr.y + 0.5f * pr.w;
        float btv = -1.0f; int bti = 0;
#pragma unroll
        for (int t = 0; t < T_NUM; ++t) {
            float ix = fminf(s_t[t][2], px1) - fmaxf(s_t[t][0], px0);
            float iy = fminf(s_t[t][3], py1) - fmaxf(s_t[t][1], py0);
            ix = fmaxf(ix, 0.0f); iy = fmaxf(iy, 0.0f);
            float ov = ix * iy;
            if (ov > btv) { btv = ov; bti = t; }          // first max over t
            if (ov > bpv[t]) { bpv[t] = ov; bpi[t] = p; } // first max over p (local)
        }
        s_bto[p] = btv;
        s_bti[p] = (short)bti;
    }
    __syncthreads();

    // block-reduce best prior per truth: (max val, min idx on tie)
#pragma unroll
    for (int t = 0; t < T_NUM; ++t) {
        float v = bpv[t]; int i = bpi[t];
#pragma unroll
        for (int off = 32; off > 0; off >>= 1) {
            float ov = __shfl_down(v, off);
            int   oi = __shfl_down(i, off);
            if (ov > v || (ov == v && oi < i)) { v = ov; i = oi; }
        }
        if (lane == 0) { s_rv[wv * T_NUM + t] = v; s_ri[wv * T_NUM + t] = i; }
    }
    __syncthreads();
    if (tid < T_NUM) {
        float v = s_rv[tid]; int i = s_ri[tid];
        for (int w = 1; w < 4; ++w) {
            float ov = s_rv[w * T_NUM + tid]; int oi = s_ri[w * T_NUM + tid];
            if (ov > v || (ov == v && oi < i)) { v = ov; i = oi; }
        }
        s_bp[tid] = i;
    }
    __syncthreads();
    // forced assignment: serial over t, last t wins (matches last_j semantics)
    if (tid == 0) {
        for (int t = 0; t < T_NUM; ++t) {
            int pb = s_bp[t];
            s_bto[pb] = 2.0f;
            s_bti[pb] = (short)t;
        }
    }
    __syncthreads();

    // conf_t + loc loss over positives
    int cnt = 0; float lsum = 0.0f;
    const float4* loc4 = (const float4*)loc;
    for (int p = tid; p < P_NUM; p += 256) {
        float ovl = s_bto[p];
        int ti = (int)s_bti[p];
        int c = (ovl < 0.5f) ? 0 : (s_lab[ti] + 1);
        conf_t[b * P_NUM + p] = c;
        if (c > 0) {
            cnt++;
            float4 pr = pr4[p];
            float mx0 = s_t[ti][0], my0 = s_t[ti][1];
            float mx1 = s_t[ti][2], my1 = s_t[ti][3];
            float gx = ((mx0 + mx1) * 0.5f - pr.x) / (0.1f * pr.z);
            float gy = ((my0 + my1) * 0.5f - pr.y) / (0.1f * pr.w);
            float gw = __logf((mx1 - mx0) / pr.z + 1e-10f) / 0.2f;
            float gh = __logf((my1 - my0) / pr.w + 1e-10f) / 0.2f;
            float4 l = loc4[b * P_NUM + p];
            lsum += smooth_l1(l.x - gx) + smooth_l1(l.y - gy)
                  + smooth_l1(l.z - gw) + smooth_l1(l.w - gh);
        }
    }
#pragma unroll
    for (int off = 32; off > 0; off >>= 1) {
        lsum += __shfl_down(lsum, off);
        cnt  += __shfl_down(cnt, off);
    }
    if (lane == 0) { s_red[wv] = lsum; s_redi[wv] = cnt; }
    __syncthreads();
    if (tid == 0) {
        float L = 0.0f; int C2 = 0;
        for (int w = 0; w < 4; ++w) { L += s_red[w]; C2 += s_redi[w]; }
        num_pos[b] = C2;
        loss_l_b[b] = L;
    }
}

// ---------------------------------------------------------------------------
// K2: cross-entropy per prior (LDS-staged, coalesced, HW-native exp/log)
// ---------------------------------------------------------------------------
__global__ __launch_bounds__(256) void k_ce(
    const float* __restrict__ conf, const int* __restrict__ conf_t,
    float* __restrict__ mined, float* __restrict__ posce_blk)
{
    __shared__ float s_c[RPB * C_NUM];   // 64*81 = 5184 floats = 20.7 KB
    __shared__ float s_red[4];
    const int blk = blockIdx.x, tid = threadIdx.x;
    const int r0 = blk * RPB;

    // coalesced float4 copy: base offset r0*81*4 bytes = 20736*blk -> 16B aligned
    const float4* src = (const float4*)(conf + (size_t)r0 * C_NUM);
    float4* dst = (float4*)s_c;
#pragma unroll 2
    for (int i = tid; i < (RPB * C_NUM) / 4; i += 256) dst[i] = src[i];
    __syncthreads();

    const int row = tid >> 2, sub = tid & 3;
    const int st = sub * 21, en = (sub == 3) ? C_NUM : (st + 21);
    const float* rp = s_c + row * C_NUM;

    float m = -FLT_MAX;
    for (int j = st; j < en; ++j) m = fmaxf(m, rp[j]);
    m = fmaxf(m, __shfl_xor(m, 1));
    m = fmaxf(m, __shfl_xor(m, 2));

    float s = 0.0f;
    for (int j = st; j < en; ++j) s += __expf(rp[j] - m);
    s += __shfl_xor(s, 1);
    s += __shfl_xor(s, 2);

    float pce = 0.0f;
    if (sub == 0) {
        int r = r0 + row;
        int c = conf_t[r];
        float ce = m + __logf(s) - rp[c];
        bool pos = c > 0;
        mined[r] = pos ? 0.0f : ce;
        if (pos) pce = ce;
    }
    const int lane = tid & 63, wv = tid >> 6;
#pragma unroll
    for (int off = 32; off > 0; off >>= 1) pce += __shfl_down(pce, off);
    if (lane == 0) s_red[wv] = pce;
    __syncthreads();
    if (tid == 0) posce_blk[blk] = s_red[0] + s_red[1] + s_red[2] + s_red[3];
}

// ---------------------------------------------------------------------------
// K3: radix-select top-nn sum per batch.
// ---------------------------------------------------------------------------
#define ELEMS 9  // ceil(8732/1024)

__global__ __launch_bounds__(1024) void k_select(
    const float* __restrict__ mined, const int* __restrict__ num_pos,
    float* __restrict__ negsum_b)
{
    __shared__ int   s_wh[16][256];   // wave-private histograms (16 KB)
    __shared__ int   s_hist[256];
    __shared__ int   s_sel, s_rem;
    __shared__ float s_sv[16];
    __shared__ int   s_sc[16];

    const int b = blockIdx.x, tid = threadIdx.x;
    const int lane = tid & 63, wv = tid >> 6;

    unsigned int val[ELEMS];
#pragma unroll
    for (int i = 0; i < ELEMS; ++i) {
        int p = tid + i * 1024;
        val[i] = (p < P_NUM) ? __float_as_uint(mined[(size_t)b * P_NUM + p]) : 0u;
    }

    int np = num_pos[b];
    int nn = 3 * np; if (nn > P_NUM - 1) nn = P_NUM - 1;
    if (nn <= 0) { if (tid == 0) negsum_b[b] = 0.0f; return; }

    unsigned int prefix = 0;
    int k = nn;
#pragma unroll
    for (int shift = 24; shift >= 0; shift -= 8) {
        for (int i = tid; i < 16 * 256; i += 1024) ((int*)s_wh)[i] = 0;
        __syncthreads();
        const unsigned int pmask = (shift == 24) ? 0u : (0xFFFFFFFFu << (shift + 8));
#pragma unroll
        for (int i = 0; i < ELEMS; ++i) {
            unsigned int v = val[i];
            if ((v & pmask) == prefix)
                atomicAdd(&s_wh[wv][(v >> shift) & 0xFF], 1);
        }
        __syncthreads();
        if (tid < 256) {
            int s = 0;
#pragma unroll
            for (int w = 0; w < 16; ++w) s += s_wh[w][tid];
            s_hist[tid] = s;
        }
        __syncthreads();
        if (wv == 0) {
            int c0 = s_hist[4 * lane + 0], c1 = s_hist[4 * lane + 1];
            int c2 = s_hist[4 * lane + 2], c3 = s_hist[4 * lane + 3];
            int t3 = c3, t2 = c2 + t3, t1 = c1 + t2, t0 = c0 + t1;
            int g = t0, G = g;
#pragma unroll
            for (int off = 1; off < 64; off <<= 1) {
                int o = __shfl_down(G, off);
                if (lane + off < 64) G += o;
            }
            int above = G - g;
            int suf0 = t0 + above, suf1 = t1 + above;
            int suf2 = t2 + above, suf3 = t3 + above, suf4 = above;
            if (suf0 >= k && suf1 < k) { s_sel = 4 * lane + 0; s_rem = k - suf1; }
            if (suf1 >= k && suf2 < k) { s_sel = 4 * lane + 1; s_rem = k - suf2; }
            if (suf2 >= k && suf3 < k) { s_sel = 4 * lane + 2; s_rem = k - suf3; }
            if (suf3 >= k && suf4 < k) { s_sel = 4 * lane + 3; s_rem = k - suf4; }
        }
        __syncthreads();
        prefix |= ((unsigned int)s_sel) << shift;
        k = s_rem;
    }

    float sgt = 0.0f; int cgt = 0;
#pragma unroll
    for (int i = 0; i < ELEMS; ++i) {
        unsigned int v = val[i];
        if (v > prefix) { sgt += __uint_as_float(v); cgt++; }
    }
#pragma unroll
    for (int off = 32; off > 0; off >>= 1) {
        sgt += __shfl_down(sgt, off);
        cgt += __shfl_down(cgt, off);
    }
    if (lane == 0) { s_sv[wv] = sgt; s_sc[wv] = cgt; }
    __syncthreads();
    if (tid == 0) {
        float S = 0.0f; int Ct = 0;
#pragma unroll
        for (int w = 0; w < 16; ++w) { S += s_sv[w]; Ct += s_sc[w]; }
        negsum_b[b] = S + (float)(nn - Ct) * __uint_as_float(prefix);
    }
}

// ---------------------------------------------------------------------------
// K4: deterministic final reduction -> out[0]=loss_l/N, out[1]=loss_c/N
// ---------------------------------------------------------------------------
__global__ __launch_bounds__(256) void k_final(
    const float* __restrict__ posce_blk, int nblk,
    const float* __restrict__ loss_l_b, const float* __restrict__ negsum_b,
    const int* __restrict__ num_pos, float* __restrict__ out)
{
    __shared__ float s_a[4], s_b[4], s_c[4];
    __shared__ int   s_i[4];
    const int tid = threadIdx.x, lane = tid & 63, wv = tid >> 6;

    float pc = 0.0f;
    for (int i = tid; i < nblk; i += 256) pc += posce_blk[i];
    float ll = 0.0f, ns = 0.0f; int np = 0;
    if (tid < B_NUM) { ll = loss_l_b[tid]; ns = negsum_b[tid]; np = num_pos[tid]; }
#pragma unroll
    for (int off = 32; off > 0; off >>= 1) {
        pc += __shfl_down(pc, off);
        ll += __shfl_down(ll, off);
        ns += __shfl_down(ns, off);
        np += __shfl_down(np, off);
    }
    if (lane == 0) { s_a[wv] = pc; s_b[wv] = ll; s_c[wv] = ns; s_i[wv] = np; }
    __syncthreads();
    if (tid == 0) {
        float PC = 0.0f, LL = 0.0f, NS = 0.0f; int NP = 0;
        for (int w = 0; w < 4; ++w) { PC += s_a[w]; LL += s_b[w]; NS += s_c[w]; NP += s_i[w]; }
        float N = (float)(NP > 1 ? NP : 1);
        out[0] = LL / N;
        out[1] = (PC + NS) / N;
    }
}

// ---------------------------------------------------------------------------
extern "C" void kernel_launch(void* const* d_in, const int* in_sizes, int n_in,
                              void* d_out, int out_size, void* d_ws, size_t ws_size,
                              hipStream_t stream) {
    const float* loc    = (const float*)d_in[0];
    const float* conf   = (const float*)d_in[1];
    const float* priors = (const float*)d_in[2];
    const float* truths = (const float*)d_in[3];
    const int*   labels = (const int*)d_in[4];
    float* out = (float*)d_out;

    int*   ws_i = (int*)d_ws;
    float* ws_f = (float*)d_ws;
    int*   num_pos   = ws_i;
    float* loss_l_b  = ws_f + 64;
    float* negsum_b  = ws_f + 128;
    float* posce_blk = ws_f + 192;
    int*   conf_t    = ws_i + 8960;
    float* mined     = ws_f + 8960 + B_NUM * P_NUM;

    k_match<<<B_NUM, 256, 0, stream>>>(loc, priors, truths, labels,
                                       conf_t, num_pos, loss_l_b);
    k_ce<<<NBLK2, 256, 0, stream>>>(conf, conf_t, mined, posce_blk);
    k_select<<<B_NUM, 1024, 0, stream>>>(mined, num_pos, negsum_b);
    k_final<<<1, 256, 0, stream>>>(posce_blk, NBLK2, loss_l_b, negsum_b, num_pos, out);
}

// Round 6
// 93.104 us; speedup vs baseline: 2.2144x; 1.1064x over previous
//
#include <hip/hip_runtime.h>
#include <float.h>
#include <math.h>

#define B_NUM 64
#define P_NUM 8732
#define T_NUM 16
#define C_NUM 81
#define RPB   64                       // rows per block in CE kernel
#define NBLK2 ((B_NUM * P_NUM) / RPB)  // 8732

__device__ __forceinline__ float smooth_l1(float d) {
    float ad = fabsf(d);
    return (ad < 1.0f) ? 0.5f * d * d : ad - 0.5f;
}

// ---------------------------------------------------------------------------
// K1: per-batch matching, conf_t, loc loss over positives (1024 thr: 9 iters)
// ---------------------------------------------------------------------------
__global__ __launch_bounds__(1024) void k_match(
    const float* __restrict__ loc, const float* __restrict__ priors,
    const float* __restrict__ truths, const int* __restrict__ labels,
    int* __restrict__ conf_t, int* __restrict__ num_pos,
    float* __restrict__ loss_l_b, int* __restrict__ sel_ctr)
{
    __shared__ float s_t[T_NUM][4];
    __shared__ int   s_lab[T_NUM];
    __shared__ float s_bto[P_NUM];
    __shared__ short s_bti[P_NUM];
    __shared__ float s_rv[16 * T_NUM];   // 16 waves x 16 truths
    __shared__ int   s_ri[16 * T_NUM];
    __shared__ int   s_bp[T_NUM];
    __shared__ float s_red[16];
    __shared__ int   s_redi[16];

    const int b = blockIdx.x;
    const int tid = threadIdx.x;
    const int lane = tid & 63, wv = tid >> 6;

    if (b == 0 && tid == 0) *sel_ctr = 0;   // reset completion counter (runs before k_select)

    if (tid < T_NUM * 4) ((float*)s_t)[tid] = truths[b * T_NUM * 4 + tid];
    if (tid < T_NUM)     s_lab[tid] = labels[b * T_NUM + tid];
    __syncthreads();

    // per-thread best prior per truth (first-occurrence: ascending p, strict >)
    float bpv[T_NUM]; int bpi[T_NUM];
#pragma unroll
    for (int t = 0; t < T_NUM; ++t) { bpv[t] = -1.0f; bpi[t] = 0; }

    const float4* pr4 = (const float4*)priors;
    for (int p = tid; p < P_NUM; p += 1024) {
        float4 pr = pr4[p];
        float px0 = pr.x - 0.5f * pr.z, py0 = pr.y - 0.5f * pr.w;
        float px1 = pr.x + 0.5f * pr.z, py1 = pr.y + 0.5f * pr.w;
        float btv = -1.0f; int bti = 0;
#pragma unroll
        for (int t = 0; t < T_NUM; ++t) {
            float ix = fminf(s_t[t][2], px1) - fmaxf(s_t[t][0], px0);
            float iy = fminf(s_t[t][3], py1) - fmaxf(s_t[t][1], py0);
            ix = fmaxf(ix, 0.0f); iy = fmaxf(iy, 0.0f);
            float ov = ix * iy;
            if (ov > btv) { btv = ov; bti = t; }          // first max over t
            if (ov > bpv[t]) { bpv[t] = ov; bpi[t] = p; } // first max over p (local)
        }
        s_bto[p] = btv;
        s_bti[p] = (short)bti;
    }
    __syncthreads();

    // wave-reduce best prior per truth: (max val, min idx on tie)
#pragma unroll
    for (int t = 0; t < T_NUM; ++t) {
        float v = bpv[t]; int i = bpi[t];
#pragma unroll
        for (int off = 32; off > 0; off >>= 1) {
            float ov = __shfl_down(v, off);
            int   oi = __shfl_down(i, off);
            if (ov > v || (ov == v && oi < i)) { v = ov; i = oi; }
        }
        if (lane == 0) { s_rv[wv * T_NUM + t] = v; s_ri[wv * T_NUM + t] = i; }
    }
    __syncthreads();
    if (tid < T_NUM) {
        float v = s_rv[tid]; int i = s_ri[tid];
        for (int w = 1; w < 16; ++w) {
            float ov = s_rv[w * T_NUM + tid]; int oi = s_ri[w * T_NUM + tid];
            if (ov > v || (ov == v && oi < i)) { v = ov; i = oi; }
        }
        s_bp[tid] = i;
    }
    __syncthreads();
    // forced assignment: serial over t, last t wins (matches last_j semantics)
    if (tid == 0) {
        for (int t = 0; t < T_NUM; ++t) {
            int pb = s_bp[t];
            s_bto[pb] = 2.0f;
            s_bti[pb] = (short)t;
        }
    }
    __syncthreads();

    // conf_t + loc loss over positives
    int cnt = 0; float lsum = 0.0f;
    const float4* loc4 = (const float4*)loc;
    for (int p = tid; p < P_NUM; p += 1024) {
        float ovl = s_bto[p];
        int ti = (int)s_bti[p];
        int c = (ovl < 0.5f) ? 0 : (s_lab[ti] + 1);
        conf_t[b * P_NUM + p] = c;
        if (c > 0) {
            cnt++;
            float4 pr = pr4[p];
            float mx0 = s_t[ti][0], my0 = s_t[ti][1];
            float mx1 = s_t[ti][2], my1 = s_t[ti][3];
            float gx = ((mx0 + mx1) * 0.5f - pr.x) / (0.1f * pr.z);
            float gy = ((my0 + my1) * 0.5f - pr.y) / (0.1f * pr.w);
            float gw = __logf((mx1 - mx0) / pr.z + 1e-10f) / 0.2f;
            float gh = __logf((my1 - my0) / pr.w + 1e-10f) / 0.2f;
            float4 l = loc4[b * P_NUM + p];
            lsum += smooth_l1(l.x - gx) + smooth_l1(l.y - gy)
                  + smooth_l1(l.z - gw) + smooth_l1(l.w - gh);
        }
    }
#pragma unroll
    for (int off = 32; off > 0; off >>= 1) {
        lsum += __shfl_down(lsum, off);
        cnt  += __shfl_down(cnt, off);
    }
    if (lane == 0) { s_red[wv] = lsum; s_redi[wv] = cnt; }
    __syncthreads();
    if (tid == 0) {
        float L = 0.0f; int C2 = 0;
        for (int w = 0; w < 16; ++w) { L += s_red[w]; C2 += s_redi[w]; }
        num_pos[b] = C2;
        loss_l_b[b] = L;
    }
}

// ---------------------------------------------------------------------------
// K2: cross-entropy per prior (LDS-staged, coalesced, HW-native exp/log)
// ---------------------------------------------------------------------------
__global__ __launch_bounds__(256) void k_ce(
    const float* __restrict__ conf, const int* __restrict__ conf_t,
    float* __restrict__ mined, float* __restrict__ posce_blk)
{
    __shared__ float s_c[RPB * C_NUM];   // 64*81 = 5184 floats = 20.7 KB
    __shared__ float s_red[4];
    const int blk = blockIdx.x, tid = threadIdx.x;
    const int r0 = blk * RPB;

    const float4* src = (const float4*)(conf + (size_t)r0 * C_NUM);
    float4* dst = (float4*)s_c;
#pragma unroll 2
    for (int i = tid; i < (RPB * C_NUM) / 4; i += 256) dst[i] = src[i];
    __syncthreads();

    const int row = tid >> 2, sub = tid & 3;
    const int st = sub * 21, en = (sub == 3) ? C_NUM : (st + 21);
    const float* rp = s_c + row * C_NUM;

    float m = -FLT_MAX;
    for (int j = st; j < en; ++j) m = fmaxf(m, rp[j]);
    m = fmaxf(m, __shfl_xor(m, 1));
    m = fmaxf(m, __shfl_xor(m, 2));

    float s = 0.0f;
    for (int j = st; j < en; ++j) s += __expf(rp[j] - m);
    s += __shfl_xor(s, 1);
    s += __shfl_xor(s, 2);

    float pce = 0.0f;
    if (sub == 0) {
        int r = r0 + row;
        int c = conf_t[r];
        float ce = m + __logf(s) - rp[c];
        bool pos = c > 0;
        mined[r] = pos ? 0.0f : ce;
        if (pos) pce = ce;
    }
    const int lane = tid & 63, wv = tid >> 6;
#pragma unroll
    for (int off = 32; off > 0; off >>= 1) pce += __shfl_down(pce, off);
    if (lane == 0) s_red[wv] = pce;
    __syncthreads();
    if (tid == 0) posce_blk[blk] = s_red[0] + s_red[1] + s_red[2] + s_red[3];
}

// ---------------------------------------------------------------------------
// K3: radix-select top-nn sum per batch + last-block final reduction.
// ---------------------------------------------------------------------------
#define ELEMS 9  // ceil(8732/1024)

__global__ __launch_bounds__(1024) void k_select(
    const float* __restrict__ mined, const int* __restrict__ num_pos,
    float* __restrict__ negsum_b, int* __restrict__ sel_ctr,
    const float* __restrict__ posce_blk, const float* __restrict__ loss_l_b,
    float* __restrict__ out)
{
    __shared__ int   s_wh[16][256];   // wave-private histograms (16 KB)
    __shared__ int   s_hist[256];
    __shared__ int   s_sel, s_rem;
    __shared__ float s_sv[16];
    __shared__ int   s_sc[16];
    __shared__ int   s_last;

    const int b = blockIdx.x, tid = threadIdx.x;
    const int lane = tid & 63, wv = tid >> 6;

    unsigned int val[ELEMS];
#pragma unroll
    for (int i = 0; i < ELEMS; ++i) {
        int p = tid + i * 1024;
        val[i] = (p < P_NUM) ? __float_as_uint(mined[(size_t)b * P_NUM + p]) : 0u;
    }

    int np = num_pos[b];
    int nn = 3 * np; if (nn > P_NUM - 1) nn = P_NUM - 1;

    if (nn > 0) {
        unsigned int prefix = 0;
        int k = nn;
#pragma unroll
        for (int shift = 24; shift >= 0; shift -= 8) {
            for (int i = tid; i < 16 * 256; i += 1024) ((int*)s_wh)[i] = 0;
            __syncthreads();
            const unsigned int pmask = (shift == 24) ? 0u : (0xFFFFFFFFu << (shift + 8));
#pragma unroll
            for (int i = 0; i < ELEMS; ++i) {
                unsigned int v = val[i];
                if ((v & pmask) == prefix)
                    atomicAdd(&s_wh[wv][(v >> shift) & 0xFF], 1);
            }
            __syncthreads();
            if (tid < 256) {
                int s = 0;
#pragma unroll
                for (int w = 0; w < 16; ++w) s += s_wh[w][tid];
                s_hist[tid] = s;
            }
            __syncthreads();
            if (wv == 0) {
                int c0 = s_hist[4 * lane + 0], c1 = s_hist[4 * lane + 1];
                int c2 = s_hist[4 * lane + 2], c3 = s_hist[4 * lane + 3];
                int t3 = c3, t2 = c2 + t3, t1 = c1 + t2, t0 = c0 + t1;
                int g = t0, G = g;
#pragma unroll
                for (int off = 1; off < 64; off <<= 1) {
                    int o = __shfl_down(G, off);
                    if (lane + off < 64) G += o;
                }
                int above = G - g;
                int suf0 = t0 + above, suf1 = t1 + above;
                int suf2 = t2 + above, suf3 = t3 + above, suf4 = above;
                if (suf0 >= k && suf1 < k) { s_sel = 4 * lane + 0; s_rem = k - suf1; }
                if (suf1 >= k && suf2 < k) { s_sel = 4 * lane + 1; s_rem = k - suf2; }
                if (suf2 >= k && suf3 < k) { s_sel = 4 * lane + 2; s_rem = k - suf3; }
                if (suf3 >= k && suf4 < k) { s_sel = 4 * lane + 3; s_rem = k - suf4; }
            }
            __syncthreads();
            prefix |= ((unsigned int)s_sel) << shift;
            k = s_rem;
        }

        float sgt = 0.0f; int cgt = 0;
#pragma unroll
        for (int i = 0; i < ELEMS; ++i) {
            unsigned int v = val[i];
            if (v > prefix) { sgt += __uint_as_float(v); cgt++; }
        }
#pragma unroll
        for (int off = 32; off > 0; off >>= 1) {
            sgt += __shfl_down(sgt, off);
            cgt += __shfl_down(cgt, off);
        }
        if (lane == 0) { s_sv[wv] = sgt; s_sc[wv] = cgt; }
        __syncthreads();
        if (tid == 0) {
            float S = 0.0f; int Ct = 0;
#pragma unroll
            for (int w = 0; w < 16; ++w) { S += s_sv[w]; Ct += s_sc[w]; }
            negsum_b[b] = S + (float)(nn - Ct) * __uint_as_float(prefix);
        }
    } else {
        if (tid == 0) negsum_b[b] = 0.0f;
    }

    // ---- completion protocol: last block performs the final reduction ----
    if (tid == 0) {
        __threadfence();                       // publish negsum_b[b]
        int old = atomicAdd(sel_ctr, 1);
        s_last = (old == B_NUM - 1) ? 1 : 0;
    }
    __syncthreads();
    if (s_last) {
        __threadfence();                       // acquire peers' negsum_b writes
        float pc = 0.0f;
        for (int i = tid; i < NBLK2; i += 1024) pc += posce_blk[i];
        float ll = 0.0f, ns = 0.0f; int npos = 0;
        if (tid < B_NUM) {
            ll = loss_l_b[tid];
            ns = negsum_b[tid];
            npos = num_pos[tid];
        }
#pragma unroll
        for (int off = 32; off > 0; off >>= 1) {
            pc += __shfl_down(pc, off);
            ll += __shfl_down(ll, off);
            ns += __shfl_down(ns, off);
            npos += __shfl_down(npos, off);
        }
        if (lane == 0) { s_sv[wv] = pc + ll; s_sc[wv] = npos; s_hist[wv] = __float_as_int(ns); }
        // pack: s_sv = pc+ll won't work for separate outputs; redo properly below
        __syncthreads();
        // recompute cleanly with three arrays (reuse s_wh rows as scratch)
        if (lane == 0) {
            ((float*)s_wh[0])[wv] = pc;
            ((float*)s_wh[1])[wv] = ll;
            ((float*)s_wh[2])[wv] = ns;
            s_wh[3][wv] = npos;
        }
        __syncthreads();
        if (tid == 0) {
            float PC = 0.0f, LL = 0.0f, NS = 0.0f; int NP = 0;
#pragma unroll
            for (int w = 0; w < 16; ++w) {
                PC += ((float*)s_wh[0])[w];
                LL += ((float*)s_wh[1])[w];
                NS += ((float*)s_wh[2])[w];
                NP += s_wh[3][w];
            }
            float N = (float)(NP > 1 ? NP : 1);
            out[0] = LL / N;
            out[1] = (PC + NS) / N;
        }
    }
}

// ---------------------------------------------------------------------------
extern "C" void kernel_launch(void* const* d_in, const int* in_sizes, int n_in,
                              void* d_out, int out_size, void* d_ws, size_t ws_size,
                              hipStream_t stream) {
    const float* loc    = (const float*)d_in[0];
    const float* conf   = (const float*)d_in[1];
    const float* priors = (const float*)d_in[2];
    const float* truths = (const float*)d_in[3];
    const int*   labels = (const int*)d_in[4];
    float* out = (float*)d_out;

    int*   ws_i = (int*)d_ws;
    float* ws_f = (float*)d_ws;
    int*   num_pos   = ws_i;             // [0,64)
    float* loss_l_b  = ws_f + 64;        // [64,128)
    float* negsum_b  = ws_f + 128;       // [128,192)
    float* posce_blk = ws_f + 192;       // [192,192+8732)
    int*   sel_ctr   = ws_i + 192 + NBLK2;        // one int
    int*   conf_t    = ws_i + 8960;
    float* mined     = ws_f + 8960 + B_NUM * P_NUM;

    k_match<<<B_NUM, 1024, 0, stream>>>(loc, priors, truths, labels,
                                        conf_t, num_pos, loss_l_b, sel_ctr);
    k_ce<<<NBLK2, 256, 0, stream>>>(conf, conf_t, mined, posce_blk);
    k_select<<<B_NUM, 1024, 0, stream>>>(mined, num_pos, negsum_b, sel_ctr,
                                         posce_blk, loss_l_b, out);
}

// Round 7
// 73.610 us; speedup vs baseline: 2.8009x; 1.2648x over previous
//
#include <hip/hip_runtime.h>
#include <float.h>
#include <math.h>

#define B_NUM 64
#define P_NUM 8732
#define T_NUM 16
#define C_NUM 81
#define TPB1  512
#define RPB_LSE 128                            // rows per lse block
#define NBLK_LSE ((B_NUM * P_NUM) / RPB_LSE)   // 4366
#define GRID1 (B_NUM + NBLK_LSE)               // 4430

__device__ __forceinline__ float smooth_l1(float d) {
    float ad = fabsf(d);
    return (ad < 1.0f) ? 0.5f * d * d : ad - 0.5f;
}

// ---------------------------------------------------------------------------
// K1 fused: blocks [0,64) = per-batch matching; blocks [64,4430) = lse+negce.
// The two roles are independent -> they overlap across CUs in one launch.
// ---------------------------------------------------------------------------
struct MatchSh {
    float s_t[T_NUM][4];
    int   s_lab[T_NUM];
    float s_bto[P_NUM];
    short s_bti[P_NUM];
    float s_rv[8 * T_NUM];
    int   s_ri[8 * T_NUM];
    int   s_bp[T_NUM];
    float s_red[8];
    int   s_redi[8];
};
struct LseSh {
    float s_c[RPB_LSE * C_NUM];    // 128*81*4 = 41.5 KB
};
union __align__(16) Sh1 { MatchSh m; LseSh l; };

__global__ __launch_bounds__(TPB1) void k_fused1(
    const float* __restrict__ loc, const float* __restrict__ conf,
    const float* __restrict__ priors, const float* __restrict__ truths,
    const int* __restrict__ labels,
    int* __restrict__ conf_t, int* __restrict__ num_pos,
    float* __restrict__ loss_l_b, float* __restrict__ lse,
    float* __restrict__ negce, int* __restrict__ sel_ctr)
{
    __shared__ Sh1 sh;
    const int tid = threadIdx.x;
    const int lane = tid & 63, wv = tid >> 6;

    if (blockIdx.x < B_NUM) {
        // ----------------- MATCH role -----------------
        const int b = blockIdx.x;
        if (b == 0 && tid == 0) *sel_ctr = 0;      // reset K2's completion counter

        if (tid < T_NUM * 4) ((float*)sh.m.s_t)[tid] = truths[b * T_NUM * 4 + tid];
        if (tid < T_NUM)     sh.m.s_lab[tid] = labels[b * T_NUM + tid];
        __syncthreads();

        float bpv[T_NUM]; int bpi[T_NUM];
#pragma unroll
        for (int t = 0; t < T_NUM; ++t) { bpv[t] = -1.0f; bpi[t] = 0; }

        const float4* pr4 = (const float4*)priors;
        for (int p = tid; p < P_NUM; p += TPB1) {
            float4 pr = pr4[p];
            float px0 = pr.x - 0.5f * pr.z, py0 = pr.y - 0.5f * pr.w;
            float px1 = pr.x + 0.5f * pr.z, py1 = pr.y + 0.5f * pr.w;
            float btv = -1.0f; int bti = 0;
#pragma unroll
            for (int t = 0; t < T_NUM; ++t) {
                float ix = fminf(sh.m.s_t[t][2], px1) - fmaxf(sh.m.s_t[t][0], px0);
                float iy = fminf(sh.m.s_t[t][3], py1) - fmaxf(sh.m.s_t[t][1], py0);
                ix = fmaxf(ix, 0.0f); iy = fmaxf(iy, 0.0f);
                float ov = ix * iy;
                if (ov > btv) { btv = ov; bti = t; }          // first max over t
                if (ov > bpv[t]) { bpv[t] = ov; bpi[t] = p; } // first max over p
            }
            sh.m.s_bto[p] = btv;
            sh.m.s_bti[p] = (short)bti;
        }
        __syncthreads();

        // reduce best prior per truth: (max val, min idx on tie)
#pragma unroll
        for (int t = 0; t < T_NUM; ++t) {
            float v = bpv[t]; int i = bpi[t];
#pragma unroll
            for (int off = 32; off > 0; off >>= 1) {
                float ov = __shfl_down(v, off);
                int   oi = __shfl_down(i, off);
                if (ov > v || (ov == v && oi < i)) { v = ov; i = oi; }
            }
            if (lane == 0) { sh.m.s_rv[wv * T_NUM + t] = v; sh.m.s_ri[wv * T_NUM + t] = i; }
        }
        __syncthreads();
        if (tid < T_NUM) {
            float v = sh.m.s_rv[tid]; int i = sh.m.s_ri[tid];
            for (int w = 1; w < 8; ++w) {
                float ov = sh.m.s_rv[w * T_NUM + tid]; int oi = sh.m.s_ri[w * T_NUM + tid];
                if (ov > v || (ov == v && oi < i)) { v = ov; i = oi; }
            }
            sh.m.s_bp[tid] = i;
        }
        __syncthreads();
        // forced assignment: serial over t, last t wins
        if (tid == 0) {
            for (int t = 0; t < T_NUM; ++t) {
                int pb = sh.m.s_bp[t];
                sh.m.s_bto[pb] = 2.0f;
                sh.m.s_bti[pb] = (short)t;
            }
        }
        __syncthreads();

        int cnt = 0; float lsum = 0.0f;
        const float4* loc4 = (const float4*)loc;
        for (int p = tid; p < P_NUM; p += TPB1) {
            float ovl = sh.m.s_bto[p];
            int ti = (int)sh.m.s_bti[p];
            int c = (ovl < 0.5f) ? 0 : (sh.m.s_lab[ti] + 1);
            conf_t[b * P_NUM + p] = c;
            if (c > 0) {
                cnt++;
                float4 pr = pr4[p];
                float mx0 = sh.m.s_t[ti][0], my0 = sh.m.s_t[ti][1];
                float mx1 = sh.m.s_t[ti][2], my1 = sh.m.s_t[ti][3];
                float gx = ((mx0 + mx1) * 0.5f - pr.x) / (0.1f * pr.z);
                float gy = ((my0 + my1) * 0.5f - pr.y) / (0.1f * pr.w);
                float gw = __logf((mx1 - mx0) / pr.z + 1e-10f) / 0.2f;
                float gh = __logf((my1 - my0) / pr.w + 1e-10f) / 0.2f;
                float4 l = loc4[b * P_NUM + p];
                lsum += smooth_l1(l.x - gx) + smooth_l1(l.y - gy)
                      + smooth_l1(l.z - gw) + smooth_l1(l.w - gh);
            }
        }
#pragma unroll
        for (int off = 32; off > 0; off >>= 1) {
            lsum += __shfl_down(lsum, off);
            cnt  += __shfl_down(cnt, off);
        }
        if (lane == 0) { sh.m.s_red[wv] = lsum; sh.m.s_redi[wv] = cnt; }
        __syncthreads();
        if (tid == 0) {
            float L = 0.0f; int C2 = 0;
            for (int w = 0; w < 8; ++w) { L += sh.m.s_red[w]; C2 += sh.m.s_redi[w]; }
            num_pos[b] = C2;
            loss_l_b[b] = L;
        }
    } else {
        // ----------------- LSE role (no dependency on matching) -----------------
        const int blk = blockIdx.x - B_NUM;
        const int r0 = blk * RPB_LSE;

        const float4* src = (const float4*)(conf + (size_t)r0 * C_NUM);
        float4* dst = (float4*)sh.l.s_c;
#pragma unroll 2
        for (int i = tid; i < (RPB_LSE * C_NUM) / 4; i += TPB1) dst[i] = src[i];
        __syncthreads();

        const int row = tid >> 2, sub = tid & 3;
        const int st = sub * 21, en = (sub == 3) ? C_NUM : (st + 21);
        const float* rp = sh.l.s_c + row * C_NUM;

        float m = -FLT_MAX;
        for (int j = st; j < en; ++j) m = fmaxf(m, rp[j]);
        m = fmaxf(m, __shfl_xor(m, 1));
        m = fmaxf(m, __shfl_xor(m, 2));

        float s = 0.0f;
        for (int j = st; j < en; ++j) s += __expf(rp[j] - m);
        s += __shfl_xor(s, 1);
        s += __shfl_xor(s, 2);

        if (sub == 0) {
            int r = r0 + row;
            float l = m + __logf(s);
            lse[r] = l;
            negce[r] = l - rp[0];      // CE when target class is 0 (negatives)
        }
    }
}

// ---------------------------------------------------------------------------
// K2: per-batch radix-select top-nn sum + positive CE gather + final reduce.
// ---------------------------------------------------------------------------
#define ELEMS 9  // ceil(8732/1024)

__global__ __launch_bounds__(1024) void k_select(
    const float* __restrict__ negce, const float* __restrict__ lse,
    const float* __restrict__ conf, const int* __restrict__ conf_t,
    const int* __restrict__ num_pos, float* __restrict__ loss_l_b,
    float* __restrict__ negsum_b, float* __restrict__ pce_b,
    int* __restrict__ sel_ctr, float* __restrict__ out)
{
    __shared__ int   s_wh[16][256];   // wave-private histograms (16 KB)
    __shared__ int   s_hist[256];
    __shared__ int   s_sel, s_rem;
    __shared__ float s_sv[16];
    __shared__ int   s_sc[16];
    __shared__ float s_pv[16];
    __shared__ int   s_last;

    const int b = blockIdx.x, tid = threadIdx.x;
    const int lane = tid & 63, wv = tid >> 6;

    // load values; positives contribute 0 to mining and accumulate pos-CE
    unsigned int val[ELEMS];
    float pce = 0.0f;
#pragma unroll
    for (int i = 0; i < ELEMS; ++i) {
        int p = tid + i * 1024;
        unsigned int v = 0u;
        if (p < P_NUM) {
            size_t idx = (size_t)b * P_NUM + p;
            int c = conf_t[idx];
            if (c == 0) {
                v = __float_as_uint(negce[idx]);
            } else {
                pce += lse[idx] - conf[idx * C_NUM + c];
            }
        }
        val[i] = v;
    }

    int np = num_pos[b];
    int nn = 3 * np; if (nn > P_NUM - 1) nn = P_NUM - 1;

    if (nn > 0) {
        unsigned int prefix = 0;
        int k = nn;
#pragma unroll
        for (int shift = 24; shift >= 0; shift -= 8) {
            for (int i = tid; i < 16 * 256; i += 1024) ((int*)s_wh)[i] = 0;
            __syncthreads();
            const unsigned int pmask = (shift == 24) ? 0u : (0xFFFFFFFFu << (shift + 8));
#pragma unroll
            for (int i = 0; i < ELEMS; ++i) {
                unsigned int v = val[i];
                if ((v & pmask) == prefix)
                    atomicAdd(&s_wh[wv][(v >> shift) & 0xFF], 1);
            }
            __syncthreads();
            if (tid < 256) {
                int s = 0;
#pragma unroll
                for (int w = 0; w < 16; ++w) s += s_wh[w][tid];
                s_hist[tid] = s;
            }
            __syncthreads();
            if (wv == 0) {
                int c0 = s_hist[4 * lane + 0], c1 = s_hist[4 * lane + 1];
                int c2 = s_hist[4 * lane + 2], c3 = s_hist[4 * lane + 3];
                int t3 = c3, t2 = c2 + t3, t1 = c1 + t2, t0 = c0 + t1;
                int g = t0, G = g;
#pragma unroll
                for (int off = 1; off < 64; off <<= 1) {
                    int o = __shfl_down(G, off);
                    if (lane + off < 64) G += o;
                }
                int above = G - g;
                int suf0 = t0 + above, suf1 = t1 + above;
                int suf2 = t2 + above, suf3 = t3 + above, suf4 = above;
                if (suf0 >= k && suf1 < k) { s_sel = 4 * lane + 0; s_rem = k - suf1; }
                if (suf1 >= k && suf2 < k) { s_sel = 4 * lane + 1; s_rem = k - suf2; }
                if (suf2 >= k && suf3 < k) { s_sel = 4 * lane + 2; s_rem = k - suf3; }
                if (suf3 >= k && suf4 < k) { s_sel = 4 * lane + 3; s_rem = k - suf4; }
            }
            __syncthreads();
            prefix |= ((unsigned int)s_sel) << shift;
            k = s_rem;
        }

        float sgt = 0.0f; int cgt = 0;
#pragma unroll
        for (int i = 0; i < ELEMS; ++i) {
            unsigned int v = val[i];
            if (v > prefix) { sgt += __uint_as_float(v); cgt++; }
        }
#pragma unroll
        for (int off = 32; off > 0; off >>= 1) {
            sgt += __shfl_down(sgt, off);
            cgt += __shfl_down(cgt, off);
        }
        if (lane == 0) { s_sv[wv] = sgt; s_sc[wv] = cgt; }
        __syncthreads();
        if (tid == 0) {
            float S = 0.0f; int Ct = 0;
#pragma unroll
            for (int w = 0; w < 16; ++w) { S += s_sv[w]; Ct += s_sc[w]; }
            negsum_b[b] = S + (float)(nn - Ct) * __uint_as_float(prefix);
        }
    } else {
        if (tid == 0) negsum_b[b] = 0.0f;
    }

    // reduce pce across block
#pragma unroll
    for (int off = 32; off > 0; off >>= 1) pce += __shfl_down(pce, off);
    if (lane == 0) s_pv[wv] = pce;
    __syncthreads();
    if (tid == 0) {
        float PCE = 0.0f;
#pragma unroll
        for (int w = 0; w < 16; ++w) PCE += s_pv[w];
        pce_b[b] = PCE;
    }

    // ---- completion protocol: last block performs the final reduction ----
    if (tid == 0) {
        __threadfence();
        int old = atomicAdd(sel_ctr, 1);
        s_last = (old == B_NUM - 1) ? 1 : 0;
    }
    __syncthreads();
    if (s_last) {
        __threadfence();
        float ll = 0.0f, ns = 0.0f, pc = 0.0f; int npos = 0;
        if (tid < B_NUM) {
            ll = loss_l_b[tid];
            ns = negsum_b[tid];
            pc = pce_b[tid];
            npos = num_pos[tid];
        }
#pragma unroll
        for (int off = 32; off > 0; off >>= 1) {
            ll += __shfl_down(ll, off);
            ns += __shfl_down(ns, off);
            pc += __shfl_down(pc, off);
            npos += __shfl_down(npos, off);
        }
        if (lane == 0) {
            ((float*)s_wh[0])[wv] = ll;
            ((float*)s_wh[1])[wv] = ns;
            ((float*)s_wh[2])[wv] = pc;
            s_wh[3][wv] = npos;
        }
        __syncthreads();
        if (tid == 0) {
            float LL = 0.0f, NS = 0.0f, PC = 0.0f; int NP = 0;
#pragma unroll
            for (int w = 0; w < 16; ++w) {
                LL += ((float*)s_wh[0])[w];
                NS += ((float*)s_wh[1])[w];
                PC += ((float*)s_wh[2])[w];
                NP += s_wh[3][w];
            }
            float N = (float)(NP > 1 ? NP : 1);
            out[0] = LL / N;
            out[1] = (PC + NS) / N;
        }
    }
}

// ---------------------------------------------------------------------------
extern "C" void kernel_launch(void* const* d_in, const int* in_sizes, int n_in,
                              void* d_out, int out_size, void* d_ws, size_t ws_size,
                              hipStream_t stream) {
    const float* loc    = (const float*)d_in[0];
    const float* conf   = (const float*)d_in[1];
    const float* priors = (const float*)d_in[2];
    const float* truths = (const float*)d_in[3];
    const int*   labels = (const int*)d_in[4];
    float* out = (float*)d_out;

    int*   ws_i = (int*)d_ws;
    float* ws_f = (float*)d_ws;
    int*   num_pos   = ws_i;                         // [0,64)
    float* loss_l_b  = ws_f + 64;                    // [64,128)
    float* negsum_b  = ws_f + 128;                   // [128,192)
    float* pce_b     = ws_f + 192;                   // [192,256)
    int*   sel_ctr   = ws_i + 256;                   // [256]
    int*   conf_t    = ws_i + 512;                   // [512, 512+BP)
    float* negce     = ws_f + 512 + B_NUM * P_NUM;   // [+BP, +2BP)
    float* lse       = ws_f + 512 + 2 * B_NUM * P_NUM;

    k_fused1<<<GRID1, TPB1, 0, stream>>>(loc, conf, priors, truths, labels,
                                         conf_t, num_pos, loss_l_b, lse, negce, sel_ctr);
    k_select<<<B_NUM, 1024, 0, stream>>>(negce, lse, conf, conf_t, num_pos,
                                         loss_l_b, negsum_b, pce_b, sel_ctr, out);
}